// Round 4
// baseline (87.591 us; speedup 1.0000x reference)
//
#include <hip/hip_runtime.h>
#include <math.h>

// nf1 box-inclusion loss — round 4: two plain kernels (no grid.sync), coalesced
// phase A, LDS byte-table screen.
//
// Round-3 post-mortem: FETCH=20.2 MB proved "2 floats/row" still touches every
// 128B line of emb (gaps 100B < line); issued as 200B-strided scalar loads it
// was a ~100-lines-per-wave divergent gather => ~16 us on 98 blocks while 158
// blocks idled at grid.sync. Fix: stream emb float4-coalesced through LDS
// tiles (proven structure), and split phases into separate dispatches for
// direct rocprof attribution.
//
// Cost model (empirical, round-2/3): divergent gather ~12 cyc/line/CU;
// coalesced streams run at BW. Mandatory traffic: emb 20 MB + pairs 16 MB
// + table broadcast 25.6 MB from L3 + ~48K rare key-gathers.
// Predicted: repack ~5 us, screen ~7-10 us.
//
// Exactness (absmax 0.0 verified rounds 0/3 with identical math):
//  - byte bucket (k=255, width 16, sentinel 255) conservative for ANY data;
//  - bucket mismatch => dim-0 disjoint => loss == 1.0 exactly;
//  - bucket match (~1.2%) => exact fp32 dim-0 key test (same ops as ref);
//  - key pass (~2e-4) => full 25-dim reference math.

#define DIMS 25
#define EMB_BOUND 10000.0f
#define FBLK 1024
#define TROWS 128
#define TFLOATS (TROWS * 2 * DIMS)

// ---------------- ultimate fallback (exact, no assumptions) ------------------
__global__ void init_ws_kernel(float* ws) {
    if (threadIdx.x == 0 && blockIdx.x == 0) ws[0] = 0.0f;
}

__global__ __launch_bounds__(256, 8) void nf1_fallback_kernel(
    const float* __restrict__ emb, const int2* __restrict__ pairs,
    int n_pairs, float* __restrict__ ws)
{
    const int gl  = threadIdx.x & 31;
    const int gid = blockIdx.x * (blockDim.x >> 5) + (threadIdx.x >> 5);
    const int ngrp = gridDim.x * (blockDim.x >> 5);
    float acc = 0.0f;
    for (int p = gid; p < n_pairs; p += ngrp) {
        int2 pr = pairs[p];
        const float* rc = emb + (size_t)pr.x * (2 * DIMS);
        const float* rd = emb + (size_t)pr.y * (2 * DIMS);
        float t = 1.0f, a = 1.0f;
        if (gl < DIMS) {
            float cc = rc[gl], co = fabsf(rc[DIMS + gl]);
            float dc = rd[gl], dd = fabsf(rd[DIMS + gl]);
            float lo = fmaxf(cc - co, dc - dd);
            float hi = fminf(cc + co, dc + dd);
            t = fmaxf(hi - lo, 0.0f);
            a = 2.0f * co;
        }
        #pragma unroll
        for (int m = 16; m >= 1; m >>= 1) { t *= __shfl_xor(t, m, 32); a *= __shfl_xor(a, m, 32); }
        float loss;
        if (a == 0.0f)     loss = 0.0f;
        else if (isinf(a)) loss = 1.0f - t / (2.0f * EMB_BOUND);
        else               loss = 1.0f - t / a;
        loss = fmaxf(loss, 0.0f);
        if (gl == 0) acc += loss * loss;
    }
    #pragma unroll
    for (int m = 32; m >= 1; m >>= 1) acc += __shfl_xor(acc, m, 64);
    __shared__ float wsum[4];
    if ((threadIdx.x & 63) == 0) wsum[threadIdx.x >> 6] = acc;
    __syncthreads();
    if (threadIdx.x == 0) atomicAdd(ws, wsum[0] + wsum[1] + wsum[2] + wsum[3]);
}

__global__ void fallback_finalize_kernel(const float* __restrict__ ws, float* __restrict__ out) {
    if (threadIdx.x == 0 && blockIdx.x == 0) out[0] = sqrtf(fmaxf(ws[0], 0.0f));
}

// ---------------- shared helpers --------------------------------------------
__device__ __forceinline__ float slow_pair(const float* __restrict__ emb, int2 pr) {
    const float* ra = emb + (size_t)pr.x * (2 * DIMS);
    const float* rb = emb + (size_t)pr.y * (2 * DIMS);
    float inter = 1.0f, carea = 1.0f;
    for (int j = 0; j < DIMS; j++) {
        float cc = ra[j], co = fabsf(ra[DIMS + j]);
        float dc = rb[j], dd = fabsf(rb[DIMS + j]);
        float lo = fmaxf(cc - co, dc - dd);
        float hi = fminf(cc + co, dc + dd);
        inter *= fmaxf(hi - lo, 0.0f);
        carea *= 2.0f * co;
    }
    float loss;
    if (carea == 0.0f)     loss = 0.0f;
    else if (isinf(carea)) loss = 1.0f - inter / (2.0f * EMB_BOUND);
    else                   loss = 1.0f - inter / carea;
    loss = fmaxf(loss, 0.0f);
    return loss * loss;
}

__device__ __forceinline__ float key_pair(const float2* __restrict__ keys,
                                          const float* __restrict__ emb, int2 pr) {
    float2 ka = keys[pr.x];
    float2 kb = keys[pr.y];
    float t0 = fminf(ka.y, kb.y) - fmaxf(ka.x, kb.x);   // exact reference dim-0
    if (t0 > 0.0f) return slow_pair(emb, pr);
    return 1.0f;                                         // loss == 1 exactly
}

template <int K>
__device__ __forceinline__ int ring_bucket(float lo, float hi) {
    float w = hi - lo;
    if (w <= 16.0f && fabsf(lo) <= 1.0e6f) {             // NaN -> sentinel
        int i = (int)floorf(lo * 0.0625f);               // width 16, exact
        int b = i % K; if (b < 0) b += K;
        return b;
    }
    return K;                                            // sentinel: always pass
}

__device__ __forceinline__ bool ring_pass(unsigned a, unsigned b, unsigned K) {
    unsigned dd = (a >= b) ? (a - b) : (b - a);
    return (a == K) | (b == K) | (dd <= 1u) | (dd == K - 1u);
}

// ---------------- kernel 1: coalesced tile repack ----------------------------
__global__ __launch_bounds__(256) void repack_tile_kernel(
    const float* __restrict__ emb, float2* __restrict__ keys,
    unsigned char* __restrict__ gbuck, int n_rows,
    float* __restrict__ acc, unsigned* __restrict__ ticket)
{
    __shared__ float tile[TFLOATS];                      // 25.6 KB
    if (blockIdx.x == 0 && threadIdx.x == 0) { acc[0] = 0.0f; ticket[0] = 0u; }
    const int n_tiles = (n_rows + TROWS - 1) / TROWS;
    for (int tIdx = blockIdx.x; tIdx < n_tiles; tIdx += gridDim.x) {
        const int r0 = tIdx * TROWS;
        const int rows = min(TROWS, n_rows - r0);
        const int cnt = rows * (2 * DIMS);
        const int n4 = cnt >> 2;
        {
            const float4* g4 = (const float4*)(emb + (size_t)r0 * (2 * DIMS));
            float4* s4 = (float4*)tile;
            for (int i = threadIdx.x; i < n4; i += blockDim.x) s4[i] = g4[i];
            for (int i = (n4 << 2) + threadIdx.x; i < cnt; i += blockDim.x)
                tile[i] = emb[(size_t)r0 * (2 * DIMS) + i];
        }
        __syncthreads();
        for (int j = threadIdx.x; j < rows; j += blockDim.x) {
            float c = tile[j * (2 * DIMS)];
            float o = fabsf(tile[j * (2 * DIMS) + DIMS]);
            float lo = c - o, hi = c + o;                // same fp32 ops as ref
            keys[r0 + j] = make_float2(lo, hi);
            gbuck[r0 + j] = (unsigned char)ring_bucket<255>(lo, hi);
        }
        __syncthreads();
    }
}

// ---------------- kernel 2: LDS byte-table screen ----------------------------
__global__ __launch_bounds__(FBLK, 1) void screen_byte_kernel(
    const float2* __restrict__ keys, const unsigned char* __restrict__ gbuck,
    const float* __restrict__ emb, const int2* __restrict__ pairs,
    int n_pairs, int n_rows, float* __restrict__ acc,
    unsigned* __restrict__ ticket, float* __restrict__ out)
{
    extern __shared__ unsigned char sbuck[];             // ~100 KB byte table
    __shared__ float wsum[FBLK / 64];
    const int nthreads = gridDim.x * blockDim.x;
    const int t = blockIdx.x * blockDim.x + threadIdx.x;
    const int noct = n_pairs >> 3;
    const int4* p4 = (const int4*)pairs;

    // issue first oct's pair loads BEFORE the broadcast barrier: their HBM
    // round-trip overlaps the table broadcast
    int4 qa, qb, qc, qd;
    const bool have0 = t < noct;
    if (have0) {
        qa = p4[4 * t + 0]; qb = p4[4 * t + 1];
        qc = p4[4 * t + 2]; qd = p4[4 * t + 3];
    }

    {   // coalesced table broadcast (global -> LDS)
        const int nb16 = (n_rows + 15) >> 4;
        const uint4* g4 = (const uint4*)gbuck;
        uint4* s4 = (uint4*)sbuck;
        for (int i = threadIdx.x; i < nb16; i += blockDim.x) s4[i] = g4[i];
    }
    __syncthreads();

    float sum = 0.0f;
    for (int q = t; q < noct; q += nthreads) {
        if (q != t) {
            qa = p4[4 * q + 0]; qb = p4[4 * q + 1];
            qc = p4[4 * q + 2]; qd = p4[4 * q + 3];
        }
        int2 pr[8] = { make_int2(qa.x, qa.y), make_int2(qa.z, qa.w),
                       make_int2(qb.x, qb.y), make_int2(qb.z, qb.w),
                       make_int2(qc.x, qc.y), make_int2(qc.z, qc.w),
                       make_int2(qd.x, qd.y), make_int2(qd.z, qd.w) };
        unsigned ba[8], bb[8];
        #pragma unroll
        for (int i = 0; i < 8; i++) { ba[i] = sbuck[pr[i].x]; bb[i] = sbuck[pr[i].y]; }
        #pragma unroll
        for (int i = 0; i < 8; i++) {
            if (ring_pass(ba[i], bb[i], 255u)) sum += key_pair(keys, emb, pr[i]); // ~1.2%
            else                               sum += 1.0f;   // certain-disjoint
        }
    }
    for (int p = (noct << 3) + t; p < n_pairs; p += nthreads) {
        int2 pr = pairs[p];
        unsigned a = sbuck[pr.x], b = sbuck[pr.y];
        if (ring_pass(a, b, 255u)) sum += key_pair(keys, emb, pr);
        else                       sum += 1.0f;
    }

    #pragma unroll
    for (int m = 32; m >= 1; m >>= 1) sum += __shfl_xor(sum, m, 64);
    if ((threadIdx.x & 63) == 0) wsum[threadIdx.x >> 6] = sum;
    __syncthreads();
    if (threadIdx.x == 0) {
        float s = 0.0f;
        #pragma unroll
        for (int w = 0; w < FBLK / 64; w++) s += wsum[w];
        atomicAdd(acc, s);
        __threadfence();
        unsigned tk = atomicAdd(ticket, 1u);
        if (tk == gridDim.x - 1)
            out[0] = sqrtf(fmaxf(atomicAdd(acc, 0.0f), 0.0f));
    }
}

extern "C" void kernel_launch(void* const* d_in, const int* in_sizes, int n_in,
                              void* d_out, int out_size, void* d_ws, size_t ws_size,
                              hipStream_t stream) {
    const float* emb  = (const float*)d_in[0];     // (100000, 50) fp32
    const int2*  prs  = (const int2*)d_in[1];      // (2000000, 2) int32
    int n_pairs = in_sizes[1] / 2;
    int n_rows  = in_sizes[0] / (2 * DIMS);

    float*    ws     = (float*)d_ws;                // ws[0]=acc, ws[1]=ticket
    unsigned* ticket = (unsigned*)(ws + 1);
    float*    out    = (float*)d_out;
    float2*   keys   = (float2*)((char*)d_ws + 256);            // 8B * n_rows
    unsigned char* gbuck = (unsigned char*)(keys + n_rows);     // byte table
    // gbuck byte offset = 256 + 8*n_rows: 16B-aligned for even n_rows.

    int dev = 0;  hipGetDevice(&dev);
    int maxShared = 0;
    hipDeviceGetAttribute(&maxShared, hipDeviceAttributeMaxSharedMemoryPerBlock, dev);

    const size_t tabBytes = (size_t)((n_rows + 15) & ~15);      // padded table
    const bool ws_ok = (ws_size >= 256 + (size_t)n_rows * 8 + tabBytes + 64) &&
                       ((n_rows & 1) == 0);
    const bool byte_ok = ((size_t)maxShared >= tabBytes + 512) && ws_ok;

    if (byte_ok) {
        const int n_tiles = (n_rows + TROWS - 1) / TROWS;
        hipLaunchKernelGGL(repack_tile_kernel, dim3(min(n_tiles, 2048)), dim3(256),
                           0, stream, emb, keys, gbuck, n_rows, ws, ticket);
        hipLaunchKernelGGL(screen_byte_kernel, dim3(256), dim3(FBLK),
                           tabBytes, stream,
                           keys, gbuck, emb, prs, n_pairs, n_rows, ws, ticket, out);
    } else {
        hipLaunchKernelGGL(init_ws_kernel, dim3(1), dim3(64), 0, stream, ws);
        hipLaunchKernelGGL(nf1_fallback_kernel, dim3(4096), dim3(256), 0, stream,
                           emb, prs, n_pairs, ws);
        hipLaunchKernelGGL(fallback_finalize_kernel, dim3(1), dim3(64), 0, stream, ws, out);
    }
}

// Round 5
// 87.072 us; speedup vs baseline: 1.0060x; 1.0060x over previous
//
#include <hip/hip_runtime.h>
#include <math.h>

// nf1 box-inclusion loss — round 5: SINGLE-VARIABLE experiment vs round 4:
// remove ALL host-side HIP API calls from kernel_launch (hipGetDevice,
// hipDeviceGetAttribute). Device kernels byte-identical to round 4.
//
// Rationale: rounds 0/3/4 (with host API queries in kernel_launch) all pin at
// dur ~87 us despite Σkernel-dispatch times of ~51/~44/~(unknown<43) us;
// round 2 (no queries) tracked kernels faithfully (142.6 = fill 43 + kernels
// 86 + 13). Micro-accounting of round-4 kernels says ~10-12 us of device
// work, leaving ~30 us unexplained — consistent with per-iteration host API
// overhead if the harness re-invokes kernel_launch each timed iteration.
// Hardcoding the byte path is safe: rounds 0/3/4 proved 100 KB dynamic LDS
// launches + verifies on this exact device (absmax 0.0).
//
// Exactness (absmax 0.0 verified rounds 0/3/4 with identical math):
//  - byte bucket (k=255, width 16, sentinel 255) conservative for ANY data;
//  - bucket mismatch => dim-0 disjoint => loss == 1.0 exactly;
//  - bucket match (~1.2%) => exact fp32 dim-0 key test (same ops as ref);
//  - key pass (~2e-4) => full 25-dim reference math.

#define DIMS 25
#define EMB_BOUND 10000.0f
#define FBLK 1024
#define TROWS 128
#define TFLOATS (TROWS * 2 * DIMS)

// ---------------- ultimate fallback (exact, no assumptions) ------------------
__global__ void init_ws_kernel(float* ws) {
    if (threadIdx.x == 0 && blockIdx.x == 0) ws[0] = 0.0f;
}

__global__ __launch_bounds__(256, 8) void nf1_fallback_kernel(
    const float* __restrict__ emb, const int2* __restrict__ pairs,
    int n_pairs, float* __restrict__ ws)
{
    const int gl  = threadIdx.x & 31;
    const int gid = blockIdx.x * (blockDim.x >> 5) + (threadIdx.x >> 5);
    const int ngrp = gridDim.x * (blockDim.x >> 5);
    float acc = 0.0f;
    for (int p = gid; p < n_pairs; p += ngrp) {
        int2 pr = pairs[p];
        const float* rc = emb + (size_t)pr.x * (2 * DIMS);
        const float* rd = emb + (size_t)pr.y * (2 * DIMS);
        float t = 1.0f, a = 1.0f;
        if (gl < DIMS) {
            float cc = rc[gl], co = fabsf(rc[DIMS + gl]);
            float dc = rd[gl], dd = fabsf(rd[DIMS + gl]);
            float lo = fmaxf(cc - co, dc - dd);
            float hi = fminf(cc + co, dc + dd);
            t = fmaxf(hi - lo, 0.0f);
            a = 2.0f * co;
        }
        #pragma unroll
        for (int m = 16; m >= 1; m >>= 1) { t *= __shfl_xor(t, m, 32); a *= __shfl_xor(a, m, 32); }
        float loss;
        if (a == 0.0f)     loss = 0.0f;
        else if (isinf(a)) loss = 1.0f - t / (2.0f * EMB_BOUND);
        else               loss = 1.0f - t / a;
        loss = fmaxf(loss, 0.0f);
        if (gl == 0) acc += loss * loss;
    }
    #pragma unroll
    for (int m = 32; m >= 1; m >>= 1) acc += __shfl_xor(acc, m, 64);
    __shared__ float wsum[4];
    if ((threadIdx.x & 63) == 0) wsum[threadIdx.x >> 6] = acc;
    __syncthreads();
    if (threadIdx.x == 0) atomicAdd(ws, wsum[0] + wsum[1] + wsum[2] + wsum[3]);
}

__global__ void fallback_finalize_kernel(const float* __restrict__ ws, float* __restrict__ out) {
    if (threadIdx.x == 0 && blockIdx.x == 0) out[0] = sqrtf(fmaxf(ws[0], 0.0f));
}

// ---------------- shared helpers --------------------------------------------
__device__ __forceinline__ float slow_pair(const float* __restrict__ emb, int2 pr) {
    const float* ra = emb + (size_t)pr.x * (2 * DIMS);
    const float* rb = emb + (size_t)pr.y * (2 * DIMS);
    float inter = 1.0f, carea = 1.0f;
    for (int j = 0; j < DIMS; j++) {
        float cc = ra[j], co = fabsf(ra[DIMS + j]);
        float dc = rb[j], dd = fabsf(rb[DIMS + j]);
        float lo = fmaxf(cc - co, dc - dd);
        float hi = fminf(cc + co, dc + dd);
        inter *= fmaxf(hi - lo, 0.0f);
        carea *= 2.0f * co;
    }
    float loss;
    if (carea == 0.0f)     loss = 0.0f;
    else if (isinf(carea)) loss = 1.0f - inter / (2.0f * EMB_BOUND);
    else                   loss = 1.0f - inter / carea;
    loss = fmaxf(loss, 0.0f);
    return loss * loss;
}

__device__ __forceinline__ float key_pair(const float2* __restrict__ keys,
                                          const float* __restrict__ emb, int2 pr) {
    float2 ka = keys[pr.x];
    float2 kb = keys[pr.y];
    float t0 = fminf(ka.y, kb.y) - fmaxf(ka.x, kb.x);   // exact reference dim-0
    if (t0 > 0.0f) return slow_pair(emb, pr);
    return 1.0f;                                         // loss == 1 exactly
}

template <int K>
__device__ __forceinline__ int ring_bucket(float lo, float hi) {
    float w = hi - lo;
    if (w <= 16.0f && fabsf(lo) <= 1.0e6f) {             // NaN -> sentinel
        int i = (int)floorf(lo * 0.0625f);               // width 16, exact
        int b = i % K; if (b < 0) b += K;
        return b;
    }
    return K;                                            // sentinel: always pass
}

__device__ __forceinline__ bool ring_pass(unsigned a, unsigned b, unsigned K) {
    unsigned dd = (a >= b) ? (a - b) : (b - a);
    return (a == K) | (b == K) | (dd <= 1u) | (dd == K - 1u);
}

// ---------------- kernel 1: coalesced tile repack ----------------------------
__global__ __launch_bounds__(256) void repack_tile_kernel(
    const float* __restrict__ emb, float2* __restrict__ keys,
    unsigned char* __restrict__ gbuck, int n_rows,
    float* __restrict__ acc, unsigned* __restrict__ ticket)
{
    __shared__ float tile[TFLOATS];                      // 25.6 KB
    if (blockIdx.x == 0 && threadIdx.x == 0) { acc[0] = 0.0f; ticket[0] = 0u; }
    const int n_tiles = (n_rows + TROWS - 1) / TROWS;
    for (int tIdx = blockIdx.x; tIdx < n_tiles; tIdx += gridDim.x) {
        const int r0 = tIdx * TROWS;
        const int rows = min(TROWS, n_rows - r0);
        const int cnt = rows * (2 * DIMS);
        const int n4 = cnt >> 2;
        {
            const float4* g4 = (const float4*)(emb + (size_t)r0 * (2 * DIMS));
            float4* s4 = (float4*)tile;
            for (int i = threadIdx.x; i < n4; i += blockDim.x) s4[i] = g4[i];
            for (int i = (n4 << 2) + threadIdx.x; i < cnt; i += blockDim.x)
                tile[i] = emb[(size_t)r0 * (2 * DIMS) + i];
        }
        __syncthreads();
        for (int j = threadIdx.x; j < rows; j += blockDim.x) {
            float c = tile[j * (2 * DIMS)];
            float o = fabsf(tile[j * (2 * DIMS) + DIMS]);
            float lo = c - o, hi = c + o;                // same fp32 ops as ref
            keys[r0 + j] = make_float2(lo, hi);
            gbuck[r0 + j] = (unsigned char)ring_bucket<255>(lo, hi);
        }
        __syncthreads();
    }
}

// ---------------- kernel 2: LDS byte-table screen ----------------------------
__global__ __launch_bounds__(FBLK, 1) void screen_byte_kernel(
    const float2* __restrict__ keys, const unsigned char* __restrict__ gbuck,
    const float* __restrict__ emb, const int2* __restrict__ pairs,
    int n_pairs, int n_rows, float* __restrict__ acc,
    unsigned* __restrict__ ticket, float* __restrict__ out)
{
    extern __shared__ unsigned char sbuck[];             // ~100 KB byte table
    __shared__ float wsum[FBLK / 64];
    const int nthreads = gridDim.x * blockDim.x;
    const int t = blockIdx.x * blockDim.x + threadIdx.x;
    const int noct = n_pairs >> 3;
    const int4* p4 = (const int4*)pairs;

    // issue first oct's pair loads BEFORE the broadcast barrier: their HBM
    // round-trip overlaps the table broadcast
    int4 qa, qb, qc, qd;
    const bool have0 = t < noct;
    if (have0) {
        qa = p4[4 * t + 0]; qb = p4[4 * t + 1];
        qc = p4[4 * t + 2]; qd = p4[4 * t + 3];
    }

    {   // coalesced table broadcast (global -> LDS)
        const int nb16 = (n_rows + 15) >> 4;
        const uint4* g4 = (const uint4*)gbuck;
        uint4* s4 = (uint4*)sbuck;
        for (int i = threadIdx.x; i < nb16; i += blockDim.x) s4[i] = g4[i];
    }
    __syncthreads();

    float sum = 0.0f;
    for (int q = t; q < noct; q += nthreads) {
        if (q != t) {
            qa = p4[4 * q + 0]; qb = p4[4 * q + 1];
            qc = p4[4 * q + 2]; qd = p4[4 * q + 3];
        }
        int2 pr[8] = { make_int2(qa.x, qa.y), make_int2(qa.z, qa.w),
                       make_int2(qb.x, qb.y), make_int2(qb.z, qb.w),
                       make_int2(qc.x, qc.y), make_int2(qc.z, qc.w),
                       make_int2(qd.x, qd.y), make_int2(qd.z, qd.w) };
        unsigned ba[8], bb[8];
        #pragma unroll
        for (int i = 0; i < 8; i++) { ba[i] = sbuck[pr[i].x]; bb[i] = sbuck[pr[i].y]; }
        #pragma unroll
        for (int i = 0; i < 8; i++) {
            if (ring_pass(ba[i], bb[i], 255u)) sum += key_pair(keys, emb, pr[i]); // ~1.2%
            else                               sum += 1.0f;   // certain-disjoint
        }
    }
    for (int p = (noct << 3) + t; p < n_pairs; p += nthreads) {
        int2 pr = pairs[p];
        unsigned a = sbuck[pr.x], b = sbuck[pr.y];
        if (ring_pass(a, b, 255u)) sum += key_pair(keys, emb, pr);
        else                       sum += 1.0f;
    }

    #pragma unroll
    for (int m = 32; m >= 1; m >>= 1) sum += __shfl_xor(sum, m, 64);
    if ((threadIdx.x & 63) == 0) wsum[threadIdx.x >> 6] = sum;
    __syncthreads();
    if (threadIdx.x == 0) {
        float s = 0.0f;
        #pragma unroll
        for (int w = 0; w < FBLK / 64; w++) s += wsum[w];
        atomicAdd(acc, s);
        __threadfence();
        unsigned tk = atomicAdd(ticket, 1u);
        if (tk == gridDim.x - 1)
            out[0] = sqrtf(fmaxf(atomicAdd(acc, 0.0f), 0.0f));
    }
}

extern "C" void kernel_launch(void* const* d_in, const int* in_sizes, int n_in,
                              void* d_out, int out_size, void* d_ws, size_t ws_size,
                              hipStream_t stream) {
    const float* emb  = (const float*)d_in[0];     // (100000, 50) fp32
    const int2*  prs  = (const int2*)d_in[1];      // (2000000, 2) int32
    int n_pairs = in_sizes[1] / 2;
    int n_rows  = in_sizes[0] / (2 * DIMS);

    float*    ws     = (float*)d_ws;                // ws[0]=acc, ws[1]=ticket
    unsigned* ticket = (unsigned*)(ws + 1);
    float*    out    = (float*)d_out;
    float2*   keys   = (float2*)((char*)d_ws + 256);            // 8B * n_rows
    unsigned char* gbuck = (unsigned char*)(keys + n_rows);     // byte table
    // gbuck byte offset = 256 + 8*n_rows: 16B-aligned for even n_rows.

    // NO host-side HIP API calls (hipGetDevice / hipDeviceGetAttribute /
    // occupancy queries) — this is the round-5 experiment variable.
    // 100 KB dynamic-LDS byte path is proven to launch + verify on this
    // device (rounds 0/3/4, absmax 0.0). Keep runtime ws-size guard +
    // exact fallback for any other environment.

    const size_t tabBytes = (size_t)((n_rows + 15) & ~15);      // padded table
    const bool byte_ok = (ws_size >= 256 + (size_t)n_rows * 8 + tabBytes + 64) &&
                         ((n_rows & 1) == 0) &&
                         (tabBytes + 512 <= 160 * 1024);        // LDS/CU cap

    if (byte_ok) {
        const int n_tiles = (n_rows + TROWS - 1) / TROWS;
        hipLaunchKernelGGL(repack_tile_kernel, dim3(min(n_tiles, 2048)), dim3(256),
                           0, stream, emb, keys, gbuck, n_rows, ws, ticket);
        hipLaunchKernelGGL(screen_byte_kernel, dim3(256), dim3(FBLK),
                           tabBytes, stream,
                           keys, gbuck, emb, prs, n_pairs, n_rows, ws, ticket, out);
    } else {
        hipLaunchKernelGGL(init_ws_kernel, dim3(1), dim3(64), 0, stream, ws);
        hipLaunchKernelGGL(nf1_fallback_kernel, dim3(4096), dim3(256), 0, stream,
                           emb, prs, n_pairs, ws);
        hipLaunchKernelGGL(fallback_finalize_kernel, dim3(1), dim3(64), 0, stream, ws, out);
    }
}